// Round 1
// baseline (3745.395 us; speedup 1.0000x reference)
//
#include <hip/hip_runtime.h>
#include <math.h>

#define DIM    768
#define BATCH  1024
#define NANS   128000
#define NTILES 500              // answer tiles of 256
#define CAND_PER_ROW (NTILES*10)

// ---------------------------------------------------------------------------
// Generic upstream GEMM: C[M,N] = A[M,K] @ W[N,K]^T + bias   (fp32)
// 64x64 tile, BK=32, 256 threads, 4x4 micro-tile.
// ---------------------------------------------------------------------------
__global__ __launch_bounds__(256, 2) void gemm_bias_k(
    const float* __restrict__ A, int lda,
    const float* __restrict__ W,
    const float* __restrict__ bias,
    float* __restrict__ C, int ldc, int K)
{
    __shared__ float as[32][68];
    __shared__ float bs[32][68];
    int m0 = blockIdx.x * 64, n0 = blockIdx.y * 64;
    int tid = threadIdx.x;
    int tm = tid & 15, tn = tid >> 4;
    int sr = tid >> 3, skq = tid & 7;
    float acc[4][4] = {};
    for (int k0 = 0; k0 < K; k0 += 32) {
        __syncthreads();
        #pragma unroll
        for (int p = 0; p < 2; ++p) {
            int r = sr + 32 * p;
            float4 av = *(const float4*)&A[(size_t)(m0 + r) * lda + k0 + skq * 4];
            as[skq*4+0][r] = av.x; as[skq*4+1][r] = av.y;
            as[skq*4+2][r] = av.z; as[skq*4+3][r] = av.w;
            float4 wv = *(const float4*)&W[(size_t)(n0 + r) * K + k0 + skq * 4];
            bs[skq*4+0][r] = wv.x; bs[skq*4+1][r] = wv.y;
            bs[skq*4+2][r] = wv.z; bs[skq*4+3][r] = wv.w;
        }
        __syncthreads();
        #pragma unroll 8
        for (int k = 0; k < 32; ++k) {
            float a4[4], b4[4];
            *(float4*)a4 = *(const float4*)&as[k][tm*4];
            *(float4*)b4 = *(const float4*)&bs[k][tn*4];
            #pragma unroll
            for (int i = 0; i < 4; ++i)
                #pragma unroll
                for (int j = 0; j < 4; ++j)
                    acc[i][j] = fmaf(a4[i], b4[j], acc[i][j]);
        }
    }
    float4 bv4 = *(const float4*)&bias[n0 + tn*4];
    #pragma unroll
    for (int i = 0; i < 4; ++i) {
        float4 c4;
        c4.x = acc[i][0] + bv4.x; c4.y = acc[i][1] + bv4.y;
        c4.z = acc[i][2] + bv4.z; c4.w = acc[i][3] + bv4.w;
        *(float4*)&C[(size_t)(m0 + tm*4 + i) * ldc + n0 + tn*4] = c4;
    }
}

// ---------------------------------------------------------------------------
__global__ void copy_visual_k(const float* __restrict__ src, float* __restrict__ dst)
{
    int idx = blockIdx.x * 256 + threadIdx.x;          // float4 index
    const int total = BATCH * (DIM / 4);
    for (; idx < total; idx += 512 * 256) {
        int b = idx / (DIM / 4), c = idx % (DIM / 4);
        ((float4*)dst)[(size_t)b * (1536 / 4) + c] = ((const float4*)src)[idx];
    }
}

// ---------------------------------------------------------------------------
__device__ __forceinline__ float block_sum(float v, float* red)
{
    #pragma unroll
    for (int o = 32; o; o >>= 1) v += __shfl_down(v, o);
    if ((threadIdx.x & 63) == 0) red[threadIdx.x >> 6] = v;
    __syncthreads();
    float r = red[0] + red[1] + red[2] + red[3];
    __syncthreads();
    return r;
}

// LayerNorm + exact GELU, in-place, one block per row (768 = 3*256)
__global__ __launch_bounds__(256) void ln_gelu_k(float* __restrict__ H,
        const float* __restrict__ g, const float* __restrict__ b)
{
    __shared__ float red[4];
    int row = blockIdx.x, tid = threadIdx.x;
    float* hr = H + (size_t)row * DIM;
    float v0 = hr[tid], v1 = hr[tid + 256], v2 = hr[tid + 512];
    float mu = block_sum(v0 + v1 + v2, red) * (1.0f / 768.0f);
    float d0 = v0 - mu, d1 = v1 - mu, d2 = v2 - mu;
    float var = block_sum(d0*d0 + d1*d1 + d2*d2, red) * (1.0f / 768.0f);
    float rinv = 1.0f / sqrtf(var + 1e-5f);
    #pragma unroll
    for (int q = 0; q < 3; ++q) {
        int d = tid + 256 * q;
        float dd = (q == 0 ? d0 : (q == 1 ? d1 : d2));
        float y = dd * rinv * g[d] + b[d];
        hr[d] = 0.5f * y * (1.0f + erff(y * 0.70710678118654752f));
    }
}

// row-wise L2 normalize, in-place
__global__ __launch_bounds__(256) void l2norm_k(float* __restrict__ P)
{
    __shared__ float red[4];
    int row = blockIdx.x, tid = threadIdx.x;
    float* pr = P + (size_t)row * DIM;
    float v0 = pr[tid], v1 = pr[tid + 256], v2 = pr[tid + 512];
    float ss = block_sum(v0*v0 + v1*v1 + v2*v2, red);
    float inv = 1.0f / fmaxf(sqrtf(ss), 1e-12f);
    pr[tid] = v0 * inv; pr[tid + 256] = v1 * inv; pr[tid + 512] = v2 * inv;
}

// answer inverse norms (fp64 accumulate), one wave per row, 4 rows/block
__global__ __launch_bounds__(256) void ans_norms_k(const float* __restrict__ ANS,
        double* __restrict__ inv64, float* __restrict__ inv32)
{
    int row = blockIdx.x * 4 + (threadIdx.x >> 6);
    int lane = threadIdx.x & 63;
    const float4* a4 = (const float4*)(ANS + (size_t)row * DIM);
    double ss = 0.0;
    #pragma unroll
    for (int q = 0; q < 3; ++q) {
        float4 x = a4[lane + 64 * q];
        ss += (double)x.x * x.x + (double)x.y * x.y
            + (double)x.z * x.z + (double)x.w * x.w;
    }
    #pragma unroll
    for (int o = 32; o; o >>= 1) ss += __shfl_down(ss, o);
    if (lane == 0) {
        double inv = 1.0 / fmax(sqrt(ss), 1e-12);
        inv64[row] = inv; inv32[row] = (float)inv;
    }
}

// ---------------------------------------------------------------------------
// Big fused kernel: fp32 GEMM (256 answers x 128 batch per block) + scale by
// inv-norm + mask + per-(row, 256-answer-tile) top-10 shortlist.
// ---------------------------------------------------------------------------
__global__ __launch_bounds__(256, 2) void big_topk_k(
    const float* __restrict__ P,       // [1024][768] normalized
    const float* __restrict__ ANS,     // [128000][768]
    const float* __restrict__ invn,    // [128000] f32
    const float* __restrict__ mask,    // [1024][128000]
    float* __restrict__ cs,            // [1024][500][10]
    int*   __restrict__ ci)
{
    __shared__ float a_lds[32][132];
    __shared__ float b_lds[32][132];
    int atile = blockIdx.x;            // 0..499
    int brow0 = blockIdx.y * 128;      // batch tile
    int tid = threadIdx.x;
    int ta = tid & 15, tb = tid >> 4;
    int sr = tid >> 3, skq = tid & 7;

    float s10[10]; int i10[10];
    #pragma unroll
    for (int q = 0; q < 10; ++q) { s10[q] = -INFINITY; i10[q] = 0x7fffffff; }

    for (int asub = 0; asub < 2; ++asub) {
        int a0 = atile * 256 + asub * 128;
        float acc[8][8] = {};
        for (int k0 = 0; k0 < 768; k0 += 32) {
            __syncthreads();
            #pragma unroll
            for (int p = 0; p < 4; ++p) {
                int r = sr + 32 * p;
                float4 av = *(const float4*)&ANS[(size_t)(a0 + r) * DIM + k0 + skq * 4];
                a_lds[skq*4+0][r] = av.x; a_lds[skq*4+1][r] = av.y;
                a_lds[skq*4+2][r] = av.z; a_lds[skq*4+3][r] = av.w;
                float4 pv = *(const float4*)&P[(size_t)(brow0 + r) * DIM + k0 + skq * 4];
                b_lds[skq*4+0][r] = pv.x; b_lds[skq*4+1][r] = pv.y;
                b_lds[skq*4+2][r] = pv.z; b_lds[skq*4+3][r] = pv.w;
            }
            __syncthreads();
            #pragma unroll 4
            for (int k = 0; k < 32; ++k) {
                float af[8], bf[8];
                *(float4*)&af[0] = *(const float4*)&a_lds[k][ta*8];
                *(float4*)&af[4] = *(const float4*)&a_lds[k][ta*8+4];
                *(float4*)&bf[0] = *(const float4*)&b_lds[k][tb*8];
                *(float4*)&bf[4] = *(const float4*)&b_lds[k][tb*8+4];
                #pragma unroll
                for (int i = 0; i < 8; ++i)
                    #pragma unroll
                    for (int j = 0; j < 8; ++j)
                        acc[i][j] = fmaf(af[i], bf[j], acc[i][j]);
            }
        }
        // scale + mask + top-10 scan, 4 slices of 32 answers via LDS reuse
        float* Cs = &a_lds[0][0];      // 32*128 floats fits in a_lds
        for (int s = 0; s < 4; ++s) {
            __syncthreads();
            if ((ta >> 2) == s) {
                int arow = (ta & 3) * 8;
                #pragma unroll
                for (int i = 0; i < 8; ++i)
                    #pragma unroll
                    for (int j = 0; j < 8; ++j)
                        Cs[(arow + i) * 128 + tb * 8 + j] = acc[i][j];
            }
            __syncthreads();
            if (tid < 128) {
                int gr = brow0 + tid;
                const float* mrow = mask + (size_t)gr * NANS;
                for (int a = 0; a < 32; ++a) {
                    int aidx = a0 + s * 32 + a;
                    float sc = Cs[a * 128 + tid] * invn[aidx] * mrow[aidx];
                    if (sc > s10[9] || (sc == s10[9] && aidx < i10[9])) {
                        s10[9] = sc; i10[9] = aidx;
                        for (int q = 9; q > 0; --q) {
                            bool sw = (s10[q] > s10[q-1]) ||
                                      (s10[q] == s10[q-1] && i10[q] < i10[q-1]);
                            if (!sw) break;
                            float ts = s10[q]; s10[q] = s10[q-1]; s10[q-1] = ts;
                            int   ti = i10[q]; i10[q] = i10[q-1]; i10[q-1] = ti;
                        }
                    }
                }
            }
        }
    }
    if (tid < 128) {
        size_t base = ((size_t)(brow0 + tid) * NTILES + atile) * 10;
        #pragma unroll
        for (int q = 0; q < 10; ++q) { cs[base + q] = s10[q]; ci[base + q] = i10[q]; }
    }
}

// ---------------------------------------------------------------------------
// Per-row: merge 5000 shortlist candidates -> top-32 (f32 order), fp64 rescore
// the 32 (mask + f64 inv-norm), final top-10 in fp64, write outputs + gather.
// ---------------------------------------------------------------------------
__global__ __launch_bounds__(256) void merge_rescore_k(
    const float* __restrict__ cs, const int* __restrict__ ci,
    const float* __restrict__ P, const float* __restrict__ ANS,
    const double* __restrict__ invn64, const float* __restrict__ mask,
    float* __restrict__ out)
{
    __shared__ float  ls[CAND_PER_ROW];
    __shared__ int    li[CAND_PER_ROW];
    __shared__ float  rrs[4];
    __shared__ int    rri[4], rrp[4];
    __shared__ int    topi_s[32];
    __shared__ double tops_s[32];
    __shared__ int    fin_s[10];
    int row = blockIdx.x, tid = threadIdx.x;

    const float* csr = cs + (size_t)row * CAND_PER_ROW;
    const int*   cir = ci + (size_t)row * CAND_PER_ROW;
    for (int i = tid; i < CAND_PER_ROW; i += 256) { ls[i] = csr[i]; li[i] = cir[i]; }
    __syncthreads();

    for (int it = 0; it < 32; ++it) {
        float bsv = -INFINITY; int bi = 0x7fffffff, bp = -1;
        for (int i = tid; i < CAND_PER_ROW; i += 256) {
            float s = ls[i];
            if (s > bsv || (s == bsv && li[i] < bi)) { bsv = s; bi = li[i]; bp = i; }
        }
        #pragma unroll
        for (int o = 32; o; o >>= 1) {
            float os = __shfl_down(bsv, o);
            int oi = __shfl_down(bi, o);
            int op = __shfl_down(bp, o);
            if (os > bsv || (os == bsv && oi < bi)) { bsv = os; bi = oi; bp = op; }
        }
        if ((tid & 63) == 0) { int w = tid >> 6; rrs[w] = bsv; rri[w] = bi; rrp[w] = bp; }
        __syncthreads();
        if (tid == 0) {
            for (int w = 1; w < 4; ++w)
                if (rrs[w] > bsv || (rrs[w] == bsv && rri[w] < bi)) {
                    bsv = rrs[w]; bi = rri[w]; bp = rrp[w];
                }
            topi_s[it] = bi;
            ls[bp] = -INFINITY;
        }
        __syncthreads();
    }

    // fp64 rescore: 8 threads per candidate
    int c = tid >> 3, part = tid & 7;
    int aidx = topi_s[c];
    const float4* p4 = (const float4*)(P + (size_t)row * DIM);
    const float4* a4 = (const float4*)(ANS + (size_t)aidx * DIM);
    double sum = 0.0;
    #pragma unroll 4
    for (int i = 0; i < 24; ++i) {
        float4 pv = p4[part * 24 + i];
        float4 av = a4[part * 24 + i];
        sum += (double)pv.x * av.x + (double)pv.y * av.y
             + (double)pv.z * av.z + (double)pv.w * av.w;
    }
    #pragma unroll
    for (int o = 4; o; o >>= 1) sum += __shfl_down(sum, o, 8);
    if (part == 0) {
        float m = mask[(size_t)row * NANS + aidx];
        tops_s[c] = sum * invn64[aidx] * (double)m;
    }
    __syncthreads();

    if (tid == 0) {
        unsigned used = 0;
        for (int k = 0; k < 10; ++k) {
            int bj = -1;
            for (int j = 0; j < 32; ++j) {
                if (used & (1u << j)) continue;
                if (bj < 0 || tops_s[j] > tops_s[bj] ||
                    (tops_s[j] == tops_s[bj] && topi_s[j] < topi_s[bj])) bj = j;
            }
            used |= 1u << bj;
            out[(size_t)row * 10 + k] = (float)tops_s[bj];
            out[10240 + (size_t)row * 10 + k] = (float)topi_s[bj];
            fin_s[k] = topi_s[bj];
        }
    }
    __syncthreads();

    for (int k = 0; k < 10; ++k) {
        int id = fin_s[k];
        const float* arow = ANS + (size_t)id * DIM;
        float* orow = out + 20480 + ((size_t)(row * 10 + k)) * DIM;
        for (int d = tid; d < DIM; d += 256) orow[d] = arow[d];
    }
}

// ---------------------------------------------------------------------------
extern "C" void kernel_launch(void* const* d_in, const int* in_sizes, int n_in,
                              void* d_out, int out_size, void* d_ws, size_t ws_size,
                              hipStream_t stream)
{
    (void)in_sizes; (void)n_in; (void)out_size; (void)ws_size;
    const float* visual = (const float*)d_in[0];
    const float* mask   = (const float*)d_in[2];
    const float* ans    = (const float*)d_in[3];
    const float* wv = (const float*)d_in[8];
    const float* bv = (const float*)d_in[9];
    const float* wo = (const float*)d_in[10];
    const float* bo = (const float*)d_in[11];
    const float* fw = (const float*)d_in[12];
    const float* fb = (const float*)d_in[13];
    const float* lg = (const float*)d_in[14];
    const float* lb = (const float*)d_in[15];
    const float* sw = (const float*)d_in[16];
    const float* sb = (const float*)d_in[17];
    float* out = (float*)d_out;

    char* w = (char*)d_ws;
    float*  fused_in = (float*)w;  w += (size_t)BATCH * 1536 * 4;
    float*  v        = (float*)w;  w += (size_t)BATCH * DIM * 4;
    float*  h        = (float*)w;  w += (size_t)BATCH * DIM * 4;
    float*  P        = (float*)w;  w += (size_t)BATCH * DIM * 4;
    double* invn64   = (double*)w; w += (size_t)NANS * 8;
    float*  invn32   = (float*)w;  w += (size_t)NANS * 4;
    float*  cs       = (float*)w;  w += (size_t)BATCH * CAND_PER_ROW * 4;
    int*    ci       = (int*)w;    w += (size_t)BATCH * CAND_PER_ROW * 4;

    copy_visual_k<<<512, 256, 0, stream>>>(visual, fused_in);
    gemm_bias_k<<<dim3(16, 12), 256, 0, stream>>>(visual, DIM, wv, bv, v, DIM, DIM);
    gemm_bias_k<<<dim3(16, 12), 256, 0, stream>>>(v, DIM, wo, bo, fused_in + DIM, 1536, DIM);
    gemm_bias_k<<<dim3(16, 12), 256, 0, stream>>>(fused_in, 1536, fw, fb, h, DIM, 1536);
    ln_gelu_k<<<BATCH, 256, 0, stream>>>(h, lg, lb);
    gemm_bias_k<<<dim3(16, 12), 256, 0, stream>>>(h, DIM, sw, sb, P, DIM, DIM);
    l2norm_k<<<BATCH, 256, 0, stream>>>(P);
    ans_norms_k<<<NANS / 4, 256, 0, stream>>>(ans, invn64, invn32);
    big_topk_k<<<dim3(NTILES, 8), 256, 0, stream>>>(P, ans, invn32, mask, cs, ci);
    merge_rescore_k<<<BATCH, 256, 0, stream>>>(cs, ci, P, ans, invn64, mask, out);
}

// Round 2
// 3461.384 us; speedup vs baseline: 1.0821x; 1.0821x over previous
//
#include <hip/hip_runtime.h>
#include <math.h>

#define DIM    768
#define BATCH  1024
#define NANS   128000
#define NTILES 500              // answer tiles of 256
#define CAND_PER_ROW (NTILES*10)

typedef short  bf16x8 __attribute__((ext_vector_type(8)));
typedef short  s16x4  __attribute__((ext_vector_type(4)));
typedef float  f32x4  __attribute__((ext_vector_type(4)));

__device__ __forceinline__ short f2bf(float x)
{
    unsigned u = __builtin_bit_cast(unsigned, x);
    u += 0x7fffu + ((u >> 16) & 1u);          // RNE (no NaN inputs here)
    return (short)(u >> 16);
}

// sorted-descending top-10 insertion, fully static indices (no scratch)
__device__ __forceinline__ void ins10(float (&s)[10], int (&ix)[10], float v, int vi)
{
    if (v > s[9] || (v == s[9] && vi < ix[9])) {
        s[9] = v; ix[9] = vi;
        #pragma unroll
        for (int q = 9; q > 0; --q) {
            bool sw = (s[q] > s[q-1]) || (s[q] == s[q-1] && ix[q] < ix[q-1]);
            float ts = s[q-1]; int ti = ix[q-1];
            s[q-1] = sw ? s[q] : s[q-1]; ix[q-1] = sw ? ix[q] : ix[q-1];
            s[q]   = sw ? ts   : s[q];   ix[q]   = sw ? ti   : ix[q];
        }
    }
}

// ---------------------------------------------------------------------------
// Generic upstream GEMM: C[M,N] = A[M,K] @ W[N,K]^T + bias   (fp32)
// ---------------------------------------------------------------------------
__global__ __launch_bounds__(256, 2) void gemm_bias_k(
    const float* __restrict__ A, int lda,
    const float* __restrict__ W,
    const float* __restrict__ bias,
    float* __restrict__ C, int ldc, int K)
{
    __shared__ float as[32][68];
    __shared__ float bs[32][68];
    int m0 = blockIdx.x * 64, n0 = blockIdx.y * 64;
    int tid = threadIdx.x;
    int tm = tid & 15, tn = tid >> 4;
    int sr = tid >> 3, skq = tid & 7;
    float acc[4][4] = {};
    for (int k0 = 0; k0 < K; k0 += 32) {
        __syncthreads();
        #pragma unroll
        for (int p = 0; p < 2; ++p) {
            int r = sr + 32 * p;
            float4 av = *(const float4*)&A[(size_t)(m0 + r) * lda + k0 + skq * 4];
            as[skq*4+0][r] = av.x; as[skq*4+1][r] = av.y;
            as[skq*4+2][r] = av.z; as[skq*4+3][r] = av.w;
            float4 wv = *(const float4*)&W[(size_t)(n0 + r) * K + k0 + skq * 4];
            bs[skq*4+0][r] = wv.x; bs[skq*4+1][r] = wv.y;
            bs[skq*4+2][r] = wv.z; bs[skq*4+3][r] = wv.w;
        }
        __syncthreads();
        #pragma unroll 8
        for (int k = 0; k < 32; ++k) {
            float a4[4], b4[4];
            *(float4*)a4 = *(const float4*)&as[k][tm*4];
            *(float4*)b4 = *(const float4*)&bs[k][tn*4];
            #pragma unroll
            for (int i = 0; i < 4; ++i)
                #pragma unroll
                for (int j = 0; j < 4; ++j)
                    acc[i][j] = fmaf(a4[i], b4[j], acc[i][j]);
        }
    }
    float4 bv4 = *(const float4*)&bias[n0 + tn*4];
    #pragma unroll
    for (int i = 0; i < 4; ++i) {
        float4 c4;
        c4.x = acc[i][0] + bv4.x; c4.y = acc[i][1] + bv4.y;
        c4.z = acc[i][2] + bv4.z; c4.w = acc[i][3] + bv4.w;
        *(float4*)&C[(size_t)(m0 + tm*4 + i) * ldc + n0 + tn*4] = c4;
    }
}

// ---------------------------------------------------------------------------
__global__ void copy_visual_k(const float* __restrict__ src, float* __restrict__ dst)
{
    int idx = blockIdx.x * 256 + threadIdx.x;          // float4 index
    const int total = BATCH * (DIM / 4);
    for (; idx < total; idx += 512 * 256) {
        int b = idx / (DIM / 4), c = idx % (DIM / 4);
        ((float4*)dst)[(size_t)b * (1536 / 4) + c] = ((const float4*)src)[idx];
    }
}

// ---------------------------------------------------------------------------
__device__ __forceinline__ float block_sum(float v, float* red)
{
    #pragma unroll
    for (int o = 32; o; o >>= 1) v += __shfl_down(v, o);
    if ((threadIdx.x & 63) == 0) red[threadIdx.x >> 6] = v;
    __syncthreads();
    float r = red[0] + red[1] + red[2] + red[3];
    __syncthreads();
    return r;
}

__global__ __launch_bounds__(256) void ln_gelu_k(float* __restrict__ H,
        const float* __restrict__ g, const float* __restrict__ b)
{
    __shared__ float red[4];
    int row = blockIdx.x, tid = threadIdx.x;
    float* hr = H + (size_t)row * DIM;
    float v0 = hr[tid], v1 = hr[tid + 256], v2 = hr[tid + 512];
    float mu = block_sum(v0 + v1 + v2, red) * (1.0f / 768.0f);
    float d0 = v0 - mu, d1 = v1 - mu, d2 = v2 - mu;
    float var = block_sum(d0*d0 + d1*d1 + d2*d2, red) * (1.0f / 768.0f);
    float rinv = 1.0f / sqrtf(var + 1e-5f);
    #pragma unroll
    for (int q = 0; q < 3; ++q) {
        int d = tid + 256 * q;
        float dd = (q == 0 ? d0 : (q == 1 ? d1 : d2));
        float y = dd * rinv * g[d] + b[d];
        hr[d] = 0.5f * y * (1.0f + erff(y * 0.70710678118654752f));
    }
}

__global__ __launch_bounds__(256) void l2norm_k(float* __restrict__ P)
{
    __shared__ float red[4];
    int row = blockIdx.x, tid = threadIdx.x;
    float* pr = P + (size_t)row * DIM;
    float v0 = pr[tid], v1 = pr[tid + 256], v2 = pr[tid + 512];
    float ss = block_sum(v0*v0 + v1*v1 + v2*v2, red);
    float inv = 1.0f / fmaxf(sqrtf(ss), 1e-12f);
    pr[tid] = v0 * inv; pr[tid + 256] = v1 * inv; pr[tid + 512] = v2 * inv;
}

__global__ __launch_bounds__(256) void ans_norms_k(const float* __restrict__ ANS,
        double* __restrict__ inv64, float* __restrict__ inv32)
{
    int row = blockIdx.x * 4 + (threadIdx.x >> 6);
    int lane = threadIdx.x & 63;
    const float4* a4 = (const float4*)(ANS + (size_t)row * DIM);
    double ss = 0.0;
    #pragma unroll
    for (int q = 0; q < 3; ++q) {
        float4 x = a4[lane + 64 * q];
        ss += (double)x.x * x.x + (double)x.y * x.y
            + (double)x.z * x.z + (double)x.w * x.w;
    }
    #pragma unroll
    for (int o = 32; o; o >>= 1) ss += __shfl_down(ss, o);
    if (lane == 0) {
        double inv = 1.0 / fmax(sqrt(ss), 1e-12);
        inv64[row] = inv; inv32[row] = (float)inv;
    }
}

// ---------------------------------------------------------------------------
// MFMA similarity + mask + per-(row, 256-answer-tile) top-10 shortlist.
// Block: 256 answers x 128 batch, 512 threads (8 waves, 2x2 of 64x64).
// ---------------------------------------------------------------------------
__global__ __launch_bounds__(512) void big_topk_mfma_k(
    const float* __restrict__ P,       // [1024][768] normalized fp32
    const float* __restrict__ ANS,     // [128000][768] fp32
    const float* __restrict__ invn,    // [128000] f32
    const float* __restrict__ mask,    // [1024][128000]
    float* __restrict__ cs,            // [1024][500][10]
    int*   __restrict__ ci)
{
    __shared__ __align__(16) char smem[40960];
    short* a_sh = (short*)smem;                 // [256][32] bf16 = 16 kB
    short* b_sh = a_sh + 256 * 32;              // [128][32] bf16 =  8 kB
    float* scl  = (float*)smem;                 // reused: [64][128] f32 = 32 kB
    float* ms   = (float*)smem;                 // reused: [128][40] f32
    int*   mi   = (int*)(smem + 20480);         // reused: [128][40] i32

    // XCD-chunked swizzle: keep the 8 batch-tiles of one answer-tile on one XCD
    int bid = blockIdx.x + blockIdx.y * gridDim.x;
    int v   = (bid & 7) * 500 + (bid >> 3);     // bijection over 4000
    int atile = v >> 3, btile = v & 7;
    int a0 = atile * 256, b0 = btile * 128;

    int t = threadIdx.x;
    int wid = t >> 6, lane = t & 63;
    int wm = wid & 3, wn = wid >> 2;            // wave grid: 4 in M x 2 in N
    int lr = lane & 15, lg = lane >> 4;

    float ainv[4];
    #pragma unroll
    for (int p = 0; p < 4; ++p) ainv[p] = invn[a0 + ((t + 512 * p) >> 3)];

    f32x4 acc[4][4];
    #pragma unroll
    for (int i = 0; i < 4; ++i)
        #pragma unroll
        for (int j = 0; j < 4; ++j)
            acc[i][j] = (f32x4){0.f, 0.f, 0.f, 0.f};

    for (int k0 = 0; k0 < 768; k0 += 32) {
        __syncthreads();
        // stage A: 256 rows x 32 k, fp32 * invn -> bf16
        #pragma unroll
        for (int p = 0; p < 4; ++p) {
            int f = t + 512 * p, r = f >> 3, kq = f & 7;
            float4 av = *(const float4*)&ANS[(size_t)(a0 + r) * DIM + k0 + kq * 4];
            s16x4 o;
            o.x = f2bf(av.x * ainv[p]); o.y = f2bf(av.y * ainv[p]);
            o.z = f2bf(av.z * ainv[p]); o.w = f2bf(av.w * ainv[p]);
            *(s16x4*)&a_sh[r * 32 + kq * 4] = o;
        }
        // stage B: 128 rows x 32 k (P already unit-norm)
        #pragma unroll
        for (int p = 0; p < 2; ++p) {
            int f = t + 512 * p, r = f >> 3, kq = f & 7;
            float4 pv = *(const float4*)&P[(size_t)(b0 + r) * DIM + k0 + kq * 4];
            s16x4 o;
            o.x = f2bf(pv.x); o.y = f2bf(pv.y);
            o.z = f2bf(pv.z); o.w = f2bf(pv.w);
            *(s16x4*)&b_sh[r * 32 + kq * 4] = o;
        }
        __syncthreads();
        bf16x8 af[4], bg[4];
        #pragma unroll
        for (int mt = 0; mt < 4; ++mt)
            af[mt] = *(bf16x8*)&a_sh[(wm * 64 + mt * 16 + lr) * 32 + lg * 8];
        #pragma unroll
        for (int nt = 0; nt < 4; ++nt)
            bg[nt] = *(bf16x8*)&b_sh[(wn * 64 + nt * 16 + lr) * 32 + lg * 8];
        #pragma unroll
        for (int mt = 0; mt < 4; ++mt)
            #pragma unroll
            for (int nt = 0; nt < 4; ++nt)
                acc[mt][nt] = __builtin_amdgcn_mfma_f32_16x16x32_bf16(
                    af[mt], bg[nt], acc[mt][nt], 0, 0, 0);
    }

    // ---- epilogue: mask + per-column top-10 over the 256-answer tile ----
    float s10[10]; int i10[10];
    #pragma unroll
    for (int q = 0; q < 10; ++q) { s10[q] = -INFINITY; i10[q] = 0x7fffffff; }
    int col = t & 127, qt = t >> 7;

    for (int c = 0; c < 4; ++c) {               // 64-row chunks
        __syncthreads();
        if (wm == c) {                          // dump chunk, mask applied
            #pragma unroll
            for (int nt = 0; nt < 4; ++nt) {
                int lcol = wn * 64 + nt * 16 + lr;
                const float* mrow = mask + (size_t)(b0 + lcol) * NANS;
                #pragma unroll
                for (int mt = 0; mt < 4; ++mt) {
                    int lrow = mt * 16 + lg * 4;
                    float4 m4 = *(const float4*)&mrow[a0 + c * 64 + lrow];
                    scl[(lrow + 0) * 128 + lcol] = acc[mt][nt][0] * m4.x;
                    scl[(lrow + 1) * 128 + lcol] = acc[mt][nt][1] * m4.y;
                    scl[(lrow + 2) * 128 + lcol] = acc[mt][nt][2] * m4.z;
                    scl[(lrow + 3) * 128 + lcol] = acc[mt][nt][3] * m4.w;
                }
            }
        }
        __syncthreads();
        #pragma unroll
        for (int i = 0; i < 16; ++i) {
            int lrow = qt * 16 + i;
            ins10(s10, i10, scl[lrow * 128 + col], a0 + c * 64 + lrow);
        }
    }

    __syncthreads();
    #pragma unroll
    for (int k = 0; k < 10; ++k) {
        ms[col * 40 + qt * 10 + k] = s10[k];
        mi[col * 40 + qt * 10 + k] = i10[k];
    }
    __syncthreads();
    if (t < 128) {
        float fs[10]; int fi[10];
        #pragma unroll
        for (int q = 0; q < 10; ++q) { fs[q] = -INFINITY; fi[q] = 0x7fffffff; }
        for (int j = 0; j < 40; ++j)
            ins10(fs, fi, ms[t * 40 + j], mi[t * 40 + j]);
        size_t base = ((size_t)(b0 + t) * NTILES + atile) * 10;
        #pragma unroll
        for (int k = 0; k < 10; ++k) { cs[base + k] = fs[k]; ci[base + k] = fi[k]; }
    }
}

// ---------------------------------------------------------------------------
// Per-row: merge 5000 candidates -> top-32 (f32), fp64 rescore, final top-10.
// ---------------------------------------------------------------------------
__global__ __launch_bounds__(256) void merge_rescore_k(
    const float* __restrict__ cs, const int* __restrict__ ci,
    const float* __restrict__ P, const float* __restrict__ ANS,
    const double* __restrict__ invn64, const float* __restrict__ mask,
    float* __restrict__ out)
{
    __shared__ float  ls[CAND_PER_ROW];
    __shared__ int    li[CAND_PER_ROW];
    __shared__ float  rrs[4];
    __shared__ int    rri[4], rrp[4];
    __shared__ int    topi_s[32];
    __shared__ double tops_s[32];
    __shared__ int    fin_s[10];
    int row = blockIdx.x, tid = threadIdx.x;

    const float* csr = cs + (size_t)row * CAND_PER_ROW;
    const int*   cir = ci + (size_t)row * CAND_PER_ROW;
    for (int i = tid; i < CAND_PER_ROW; i += 256) { ls[i] = csr[i]; li[i] = cir[i]; }
    __syncthreads();

    for (int it = 0; it < 32; ++it) {
        float bsv = -INFINITY; int bi = 0x7fffffff, bp = -1;
        for (int i = tid; i < CAND_PER_ROW; i += 256) {
            float s = ls[i];
            if (s > bsv || (s == bsv && li[i] < bi)) { bsv = s; bi = li[i]; bp = i; }
        }
        #pragma unroll
        for (int o = 32; o; o >>= 1) {
            float os = __shfl_down(bsv, o);
            int oi = __shfl_down(bi, o);
            int op = __shfl_down(bp, o);
            if (os > bsv || (os == bsv && oi < bi)) { bsv = os; bi = oi; bp = op; }
        }
        if ((tid & 63) == 0) { int w = tid >> 6; rrs[w] = bsv; rri[w] = bi; rrp[w] = bp; }
        __syncthreads();
        if (tid == 0) {
            for (int w = 1; w < 4; ++w)
                if (rrs[w] > bsv || (rrs[w] == bsv && rri[w] < bi)) {
                    bsv = rrs[w]; bi = rri[w]; bp = rrp[w];
                }
            topi_s[it] = bi;
            ls[bp] = -INFINITY;
        }
        __syncthreads();
    }

    int c = tid >> 3, part = tid & 7;
    int aidx = topi_s[c];
    const float4* p4 = (const float4*)(P + (size_t)row * DIM);
    const float4* a4 = (const float4*)(ANS + (size_t)aidx * DIM);
    double sum = 0.0;
    #pragma unroll 4
    for (int i = 0; i < 24; ++i) {
        float4 pv = p4[part * 24 + i];
        float4 av = a4[part * 24 + i];
        sum += (double)pv.x * av.x + (double)pv.y * av.y
             + (double)pv.z * av.z + (double)pv.w * av.w;
    }
    #pragma unroll
    for (int o = 4; o; o >>= 1) sum += __shfl_down(sum, o, 8);
    if (part == 0) {
        float m = mask[(size_t)row * NANS + aidx];
        tops_s[c] = sum * invn64[aidx] * (double)m;
    }
    __syncthreads();

    if (tid == 0) {
        unsigned used = 0;
        for (int k = 0; k < 10; ++k) {
            int bj = -1;
            for (int j = 0; j < 32; ++j) {
                if (used & (1u << j)) continue;
                if (bj < 0 || tops_s[j] > tops_s[bj] ||
                    (tops_s[j] == tops_s[bj] && topi_s[j] < topi_s[bj])) bj = j;
            }
            used |= 1u << bj;
            out[(size_t)row * 10 + k] = (float)tops_s[bj];
            out[10240 + (size_t)row * 10 + k] = (float)topi_s[bj];
            fin_s[k] = topi_s[bj];
        }
    }
    __syncthreads();

    for (int k = 0; k < 10; ++k) {
        int id = fin_s[k];
        const float* arow = ANS + (size_t)id * DIM;
        float* orow = out + 20480 + ((size_t)(row * 10 + k)) * DIM;
        for (int d = tid; d < DIM; d += 256) orow[d] = arow[d];
    }
}

// ---------------------------------------------------------------------------
extern "C" void kernel_launch(void* const* d_in, const int* in_sizes, int n_in,
                              void* d_out, int out_size, void* d_ws, size_t ws_size,
                              hipStream_t stream)
{
    (void)in_sizes; (void)n_in; (void)out_size; (void)ws_size;
    const float* visual = (const float*)d_in[0];
    const float* mask   = (const float*)d_in[2];
    const float* ans    = (const float*)d_in[3];
    const float* wv = (const float*)d_in[8];
    const float* bv = (const float*)d_in[9];
    const float* wo = (const float*)d_in[10];
    const float* bo = (const float*)d_in[11];
    const float* fw = (const float*)d_in[12];
    const float* fb = (const float*)d_in[13];
    const float* lg = (const float*)d_in[14];
    const float* lb = (const float*)d_in[15];
    const float* sw = (const float*)d_in[16];
    const float* sb = (const float*)d_in[17];
    float* out = (float*)d_out;

    char* w = (char*)d_ws;
    float*  fused_in = (float*)w;  w += (size_t)BATCH * 1536 * 4;
    float*  v        = (float*)w;  w += (size_t)BATCH * DIM * 4;
    float*  h        = (float*)w;  w += (size_t)BATCH * DIM * 4;
    float*  P        = (float*)w;  w += (size_t)BATCH * DIM * 4;
    double* invn64   = (double*)w; w += (size_t)NANS * 8;
    float*  invn32   = (float*)w;  w += (size_t)NANS * 4;
    float*  cs       = (float*)w;  w += (size_t)BATCH * CAND_PER_ROW * 4;
    int*    ci       = (int*)w;    w += (size_t)BATCH * CAND_PER_ROW * 4;

    copy_visual_k<<<512, 256, 0, stream>>>(visual, fused_in);
    gemm_bias_k<<<dim3(16, 12), 256, 0, stream>>>(visual, DIM, wv, bv, v, DIM, DIM);
    gemm_bias_k<<<dim3(16, 12), 256, 0, stream>>>(v, DIM, wo, bo, fused_in + DIM, 1536, DIM);
    gemm_bias_k<<<dim3(16, 12), 256, 0, stream>>>(fused_in, 1536, fw, fb, h, DIM, 1536);
    ln_gelu_k<<<BATCH, 256, 0, stream>>>(h, lg, lb);
    gemm_bias_k<<<dim3(16, 12), 256, 0, stream>>>(h, DIM, sw, sb, P, DIM, DIM);
    l2norm_k<<<BATCH, 256, 0, stream>>>(P);
    ans_norms_k<<<NANS / 4, 256, 0, stream>>>(ans, invn64, invn32);
    big_topk_mfma_k<<<dim3(4000), 512, 0, stream>>>(P, ans, invn32, mask, cs, ci);
    merge_rescore_k<<<BATCH, 256, 0, stream>>>(cs, ci, P, ans, invn64, mask, out);
}